// Round 1
// 243.594 us; speedup vs baseline: 1.0466x; 1.0466x over previous
//
#include <hip/hip_runtime.h>

// Dense 2D spatial transformer (bilinear warp, dense flow), 4096x4096 f32.
//
// Round 5: paired-tap gathers. R4 post-mortem: HBM 31%, VALU 34%, occ 72%,
// 0 bank conflicts -- nothing saturated. Remaining bottleneck is vL1D/TA
// gather service: 16 address-divergent dword gathers per 4-pixel batch,
// each costing ~10-20 cache-line transactions (flow ~N(0,1) spreads the 64
// lanes over ~4-6 rows).
//
// Fix: for each pixel the two taps in a row are ADJACENT floats
// (cc = cf+1 away from borders), so (v00,v01) and (v10,v11) each become a
// single dwordx2 gather from a clamped pair base cb = clamp(cf,0,W-2).
// Border misalignment of the pair is absorbed into the WEIGHTS via {0,1}
// selectors (cndmask), keeping all loads branch-free. Pair loads are only
// 4B-aligned -> aligned(4) ext-vector type (gfx950 supports unaligned
// global; worst case the compiler splits to 2 dwords = old behavior).
// Also 2 columns per thread: flow loads and out stores become float2.
// Net VMEM: 7 -> 3.5 instructions/pixel, tap line-transactions ~halved.
//
// Reference math replicated exactly (same as passing R1-R4):
//   H_up=(flow_h+h)+1 ; W_up=(flow_w+w)+1 ; hf=floor, hc=hf+1, clamp to
//   [0,H+1] (padded dims); dH=(float)hc_clamped-H_up (clamp BEFORE weights);
//   out = v00*(dW*dH)+v10*(dW*(1-dH))+v01*((1-dW)*dH)+v11*((1-dW)*(1-dH));
//   taps outside the image contribute 0 (zero-pad border) via zeroed weights.

#define IMG_H 4096
#define IMG_W 4096

typedef float f2  __attribute__((ext_vector_type(2)));              // 8B-aligned
typedef float f2u __attribute__((ext_vector_type(2), aligned(4)));  // 4B-aligned pair

__global__ __launch_bounds__(256) void warp_bilinear_kernel(
    const float* __restrict__ img,   // [H, W]
    const float* __restrict__ flow,  // [2, H, W]
    float* __restrict__ out)         // [H, W]
{
    const int HW   = IMG_H * IMG_W;
    const int lane = threadIdx.x & 63;
    const int wv   = threadIdx.x >> 6;              // 0..3
    const int w0   = blockIdx.x * 128 + lane * 2;   // 2 cols/thread, even -> f2 aligned
    const int h0   = blockIdx.y * 8 + wv * 2;       // 2 rows/thread

    int rowidx[2];
    rowidx[0] = h0 * IMG_W + w0;
    rowidx[1] = rowidx[0] + IMG_W;

    // ---- phase 1: issue all 4 flow loads (float2, coalesced, streaming) ----
    f2 fh[2], fw[2];
    #pragma unroll
    for (int r = 0; r < 2; ++r)
        fh[r] = __builtin_nontemporal_load((const f2*)(flow + rowidx[r]));
    #pragma unroll
    for (int r = 0; r < 2; ++r)
        fw[r] = __builtin_nontemporal_load((const f2*)(flow + HW + rowidx[r]));

    // ---- phase 2: pair-base addresses + selector-folded weights ----
    // Per pixel: pair base col cb = clamp(cf,0,W-2); element selectors
    // sf = cf_cl-cb, sc = cc_cl-cb (each in {0,1}, proven: interior sf=0,sc=1;
    // cf=-1 -> sf=sc=0; cf=W-1 -> sf=sc=1; out-of-range taps have zero weight).
    int   o0[2][2], o1[2][2];
    float a0x[2][2], a0y[2][2], a1x[2][2], a1y[2][2];

    #pragma unroll
    for (int r = 0; r < 2; ++r) {
        #pragma unroll
        for (int c = 0; c < 2; ++c) {
            const int h = h0 + r;
            const int w = w0 + c;
            // exact reference grouping: (flow + mesh) + 1.0
            float Hu = (fh[r][c] + (float)h) + 1.0f;
            float Wu = (fw[r][c] + (float)w) + 1.0f;

            int hf = (int)floorf(Hu);
            int wf = (int)floorf(Wu);
            int hc = hf + 1;
            int wc = wf + 1;

            // clamp to padded range [0, H+1]; weights use CLAMPED indices
            int hfc = min(max(hf, 0), IMG_H + 1);
            int hcc = min(max(hc, 0), IMG_H + 1);
            int wfc = min(max(wf, 0), IMG_W + 1);
            int wcc = min(max(wc, 0), IMG_W + 1);

            float dH = (float)hcc - Hu;
            float dW = (float)wcc - Wu;

            // padded coord p -> img coord p-1; validity
            int rf = hfc - 1, rc = hcc - 1, cf = wfc - 1, cc = wcc - 1;
            bool rf_in = (unsigned)rf < IMG_H;
            bool rc_in = (unsigned)rc < IMG_H;
            bool cf_in = (unsigned)cf < IMG_W;
            bool cc_in = (unsigned)cc < IMG_W;

            int rf_cl = min(max(rf, 0), IMG_H - 1);
            int rc_cl = min(max(rc, 0), IMG_H - 1);
            int cf_cl = min(max(cf, 0), IMG_W - 1);
            int cc_cl = min(max(cc, 0), IMG_W - 1);
            int cb    = min(max(cf, 0), IMG_W - 2);   // float2 pair base

            int sf = cf_cl - cb;   // 0 or 1
            int sc = cc_cl - cb;   // 0 or 1

            o0[r][c] = (rf_cl << 12) + cb;
            o1[r][c] = (rc_cl << 12) + cb;

            float A = dW * dH;
            float B = dW * (1.0f - dH);
            float C = (1.0f - dW) * dH;
            float D = (1.0f - dW) * (1.0f - dH);
            // zero-pad border: out-of-image tap contributes 0 via its weight
            float w00 = (rf_in && cf_in) ? A : 0.0f;   // (rf, cf)
            float w10 = (rc_in && cf_in) ? B : 0.0f;   // (rc, cf)
            float w01 = (rf_in && cc_in) ? C : 0.0f;   // (rf, cc)
            float w11 = (rc_in && cc_in) ? D : 0.0f;   // (rc, cc)

            // fold selectors into per-element weights of each float2 pair
            a0x[r][c] = (sf ? 0.0f : w00) + (sc ? 0.0f : w01);
            a0y[r][c] = (sf ? w00 : 0.0f) + (sc ? w01 : 0.0f);
            a1x[r][c] = (sf ? 0.0f : w10) + (sc ? 0.0f : w11);
            a1y[r][c] = (sf ? w10 : 0.0f) + (sc ? w11 : 0.0f);
        }
    }

    // ---- phase 3: issue all 8 paired gathers (branch-free, batched) ----
    f2u p0[2][2], p1[2][2];
    #pragma unroll
    for (int r = 0; r < 2; ++r) {
        #pragma unroll
        for (int c = 0; c < 2; ++c) {
            p0[r][c] = *(const f2u*)(img + o0[r][c]);
            p1[r][c] = *(const f2u*)(img + o1[r][c]);
        }
    }

    // ---- phase 4: blend + float2 store ----
    #pragma unroll
    for (int r = 0; r < 2; ++r) {
        f2 res;
        #pragma unroll
        for (int c = 0; c < 2; ++c) {
            res[c] = p0[r][c].x * a0x[r][c] + p0[r][c].y * a0y[r][c]
                   + p1[r][c].x * a1x[r][c] + p1[r][c].y * a1y[r][c];
        }
        __builtin_nontemporal_store(res, (f2*)(out + rowidx[r]));
    }
}

extern "C" void kernel_launch(void* const* d_in, const int* in_sizes, int n_in,
                              void* d_out, int out_size, void* d_ws, size_t ws_size,
                              hipStream_t stream) {
    const float* img  = (const float*)d_in[0];   // [1,1,4096,4096]
    const float* flow = (const float*)d_in[1];   // [1,2,4096,4096]
    float* out = (float*)d_out;                  // [1,1,4096,4096]

    dim3 grid(IMG_W / 128, IMG_H / 8);           // (32, 512)
    dim3 block(256);
    warp_bilinear_kernel<<<grid, block, 0, stream>>>(img, flow, out);
}

// Round 2
// 239.059 us; speedup vs baseline: 1.0665x; 1.0190x over previous
//
#include <hip/hip_runtime.h>

// Dense 2D spatial transformer (bilinear warp, dense flow), 4096x4096 f32.
//
// Round 6: LDS-staged gather. R5 post-mortem: pairing taps gave 78.6->~67us,
// matching the line-transaction model of the vL1D/TA pipe (R4 ~256 lines/wave
// -> R5 ~224, dur ratio 0.85 ~= 224/256). HBM floor is only ~30us, so the
// remaining 2.2x sits in TA gather service.
//
// Fix: flow ~N(0,1), so a 128x16 output tile's taps live in a 144x32 image
// window (halo +-8) with probability 1-1e-13. Stage that window in LDS (18KB)
// via fully-coalesced float4 loads (every staged line is a fully-utilized TA
// transaction), then gather from LDS (ds_read2_b32 pairs) -- the LDS pipe
// runs in parallel with TA, and random addresses over 32 banks average only
// ~4 accesses/bank. The rare tail (any tap outside the window) falls back
// per-lane to the identical global-gather path, preserving exactness.
//
// Reference math replicated exactly (verbatim from passing R5):
//   H_up=(flow_h+h)+1 ; W_up=(flow_w+w)+1 ; hf=floor, hc=hf+1, clamp to
//   [0,H+1] (padded dims); dH=(float)hc_clamped-H_up (clamp BEFORE weights);
//   out = v00*(dW*dH)+v10*(dW*(1-dH))+v01*((1-dW)*dH)+v11*((1-dW)*(1-dH));
//   taps outside the image contribute 0 (zero-pad border) via zeroed weights;
//   row taps paired as (v00,v01)/(v10,v11) float2 from base cb=clamp(cf,0,W-2)
//   with {0,1} selectors folded into the weights.

#define IMG_H 4096
#define IMG_W 4096
#define TR 16                 // output rows per block
#define TC 128                // output cols per block
#define HALO 8
#define SR (TR + 2 * HALO)    // 32 staged rows
#define SC (TC + 2 * HALO)    // 144 staged cols (36 float4 per row)
#define SC4 (SC / 4)
#define NCHUNK (SR * SC4)     // 1152 float4 stage chunks

typedef float f2  __attribute__((ext_vector_type(2)));              // 8B-aligned
typedef float f2u __attribute__((ext_vector_type(2), aligned(4)));  // 4B-aligned pair
typedef float f4  __attribute__((ext_vector_type(4)));

__global__ __launch_bounds__(256) void warp_bilinear_kernel(
    const float* __restrict__ img,   // [H, W]
    const float* __restrict__ flow,  // [2, H, W]
    float* __restrict__ out)         // [H, W]
{
    __shared__ float tile[SR * SC];  // 18432 B

    const int HW   = IMG_H * IMG_W;
    const int tid  = threadIdx.x;
    const int lane = tid & 63;
    const int wv   = tid >> 6;                      // 0..3
    const int w0   = blockIdx.x * TC + lane * 2;    // 2 cols/thread (even)
    const int h0   = blockIdx.y * TR + wv * 4;      // 4 rows/thread
    const int r_lo = blockIdx.y * TR - HALO;        // staged window origin (row)
    const int c_lo = blockIdx.x * TC - HALO;        // staged window origin (col)

    // ---- stage image window into LDS (coalesced float4, L2-cached) ----
    // Window rows/cols outside [0,4095] load a clamped address; those LDS
    // slots are never read (taps are clamped into [0,4095] themselves).
    #pragma unroll
    for (int it = 0; it < 5; ++it) {
        int t = tid + it * 256;
        if (t < NCHUNK) {
            int i  = t / SC4;                        // staged row 0..31
            int m  = t - i * SC4;                    // f4 chunk 0..35
            int gr = min(max(r_lo + i, 0), IMG_H - 1);
            int gc = min(max(c_lo + 4 * m, 0), IMG_W - 4);
            f4 v = *(const f4*)(img + gr * IMG_W + gc);
            *(f4*)(tile + i * SC + 4 * m) = v;
        }
    }

    // ---- flow loads (all 8, streaming; issued before the barrier) ----
    int rowidx[4];
    f2  fh[4], fw[4];
    #pragma unroll
    for (int r = 0; r < 4; ++r)
        rowidx[r] = (h0 + r) * IMG_W + w0;
    #pragma unroll
    for (int r = 0; r < 4; ++r)
        fh[r] = __builtin_nontemporal_load((const f2*)(flow + rowidx[r]));
    #pragma unroll
    for (int r = 0; r < 4; ++r)
        fw[r] = __builtin_nontemporal_load((const f2*)(flow + HW + rowidx[r]));

    __syncthreads();

    // ---- process 8 px in two 2-row groups (caps live registers) ----
    #pragma unroll
    for (int g = 0; g < 2; ++g) {
        int   li0[2][2], li1[2][2];                  // LDS pair indices
        int   ob0[2][2], ob1[2][2];                  // global pair offsets (fallback)
        float a0x[2][2], a0y[2][2], a1x[2][2], a1y[2][2];
        bool  ok = true;

        #pragma unroll
        for (int rr = 0; rr < 2; ++rr) {
            const int r = 2 * g + rr;
            #pragma unroll
            for (int c = 0; c < 2; ++c) {
                const int h = h0 + r;
                const int w = w0 + c;
                // exact reference grouping: (flow + mesh) + 1.0
                float Hu = (fh[r][c] + (float)h) + 1.0f;
                float Wu = (fw[r][c] + (float)w) + 1.0f;

                int hf = (int)floorf(Hu);
                int wf = (int)floorf(Wu);
                int hc = hf + 1;
                int wc = wf + 1;

                // clamp to padded range [0, H+1]; weights use CLAMPED indices
                int hfc = min(max(hf, 0), IMG_H + 1);
                int hcc = min(max(hc, 0), IMG_H + 1);
                int wfc = min(max(wf, 0), IMG_W + 1);
                int wcc = min(max(wc, 0), IMG_W + 1);

                float dH = (float)hcc - Hu;
                float dW = (float)wcc - Wu;

                // padded coord p -> img coord p-1; validity
                int rf = hfc - 1, rc = hcc - 1, cf = wfc - 1, cc = wcc - 1;
                bool rf_in = (unsigned)rf < IMG_H;
                bool rc_in = (unsigned)rc < IMG_H;
                bool cf_in = (unsigned)cf < IMG_W;
                bool cc_in = (unsigned)cc < IMG_W;

                int rf_cl = min(max(rf, 0), IMG_H - 1);
                int rc_cl = min(max(rc, 0), IMG_H - 1);
                int cf_cl = min(max(cf, 0), IMG_W - 1);
                int cc_cl = min(max(cc, 0), IMG_W - 1);
                int cb    = min(max(cf, 0), IMG_W - 2);   // float2 pair base

                int sf = cf_cl - cb;   // 0 or 1
                int sc = cc_cl - cb;   // 0 or 1

                // staged-window coordinates + in-window predicate
                int i0 = rf_cl - r_lo;
                int i1 = rc_cl - r_lo;
                int jb = cb - c_lo;
                ok = ok && ((unsigned)i0 < SR) && ((unsigned)i1 < SR)
                        && ((unsigned)jb < (SC - 1));
                li0[rr][c] = i0 * SC + jb;
                li1[rr][c] = i1 * SC + jb;
                ob0[rr][c] = (rf_cl << 12) + cb;
                ob1[rr][c] = (rc_cl << 12) + cb;

                float A = dW * dH;
                float B = dW * (1.0f - dH);
                float C = (1.0f - dW) * dH;
                float D = (1.0f - dW) * (1.0f - dH);
                // zero-pad border: out-of-image tap contributes 0 via weight
                float w00 = (rf_in && cf_in) ? A : 0.0f;   // (rf, cf)
                float w10 = (rc_in && cf_in) ? B : 0.0f;   // (rc, cf)
                float w01 = (rf_in && cc_in) ? C : 0.0f;   // (rf, cc)
                float w11 = (rc_in && cc_in) ? D : 0.0f;   // (rc, cc)

                // fold pair-element selectors into per-element weights
                a0x[rr][c] = (sf ? 0.0f : w00) + (sc ? 0.0f : w01);
                a0y[rr][c] = (sf ? w00 : 0.0f) + (sc ? w01 : 0.0f);
                a1x[rr][c] = (sf ? 0.0f : w10) + (sc ? 0.0f : w11);
                a1y[rr][c] = (sf ? w10 : 0.0f) + (sc ? w11 : 0.0f);
            }
        }

        // ---- gathers: LDS fast path, global fallback (P ~ 1e-13) ----
        float q0x[2][2], q0y[2][2], q1x[2][2], q1y[2][2];
        if (__builtin_expect(ok, 1)) {
            #pragma unroll
            for (int rr = 0; rr < 2; ++rr)
                #pragma unroll
                for (int c = 0; c < 2; ++c) {
                    q0x[rr][c] = tile[li0[rr][c]];
                    q0y[rr][c] = tile[li0[rr][c] + 1];
                    q1x[rr][c] = tile[li1[rr][c]];
                    q1y[rr][c] = tile[li1[rr][c] + 1];
                }
        } else {
            #pragma unroll
            for (int rr = 0; rr < 2; ++rr)
                #pragma unroll
                for (int c = 0; c < 2; ++c) {
                    f2u p0 = *(const f2u*)(img + ob0[rr][c]);
                    f2u p1 = *(const f2u*)(img + ob1[rr][c]);
                    q0x[rr][c] = p0.x; q0y[rr][c] = p0.y;
                    q1x[rr][c] = p1.x; q1y[rr][c] = p1.y;
                }
        }

        // ---- blend + float2 store (same expression tree as R5) ----
        #pragma unroll
        for (int rr = 0; rr < 2; ++rr) {
            f2 res;
            #pragma unroll
            for (int c = 0; c < 2; ++c) {
                res[c] = q0x[rr][c] * a0x[rr][c] + q0y[rr][c] * a0y[rr][c]
                       + q1x[rr][c] * a1x[rr][c] + q1y[rr][c] * a1y[rr][c];
            }
            __builtin_nontemporal_store(res, (f2*)(out + rowidx[2 * g + rr]));
        }
    }
}

extern "C" void kernel_launch(void* const* d_in, const int* in_sizes, int n_in,
                              void* d_out, int out_size, void* d_ws, size_t ws_size,
                              hipStream_t stream) {
    const float* img  = (const float*)d_in[0];   // [1,1,4096,4096]
    const float* flow = (const float*)d_in[1];   // [1,2,4096,4096]
    float* out = (float*)d_out;                  // [1,1,4096,4096]

    dim3 grid(IMG_W / TC, IMG_H / TR);           // (32, 256)
    dim3 block(256);
    warp_bilinear_kernel<<<grid, block, 0, stream>>>(img, flow, out);
}